// Round 2
// 1440.054 us; speedup vs baseline: 1.1107x; 1.1107x over previous
//
#include <hip/hip_runtime.h>
#include <math.h>

#define BB 2
#define SS 2048
#define DMM 1024
#define HH 16
#define DDEP 64

typedef unsigned short u16;
typedef __attribute__((ext_vector_type(8))) short bf16x8;
typedef __attribute__((ext_vector_type(8))) unsigned short u16x8;
typedef __attribute__((ext_vector_type(4))) float f32x4;

// Split fp32 into truncated-bf16 hi + bf16(lo remainder). a ~= hi + lo with
// |a - hi - lo| <= 2^-16 |a|;  (ah+al)(bh+bl) ~= ah*bh + ah*bl + al*bh (drop lo*lo).
__device__ __forceinline__ void bsplit(float x, u16& h, u16& l) {
  unsigned u = __float_as_uint(x);
  h = (u16)(u >> 16);
  float hf = __uint_as_float(u & 0xFFFF0000u);
  l = (u16)(__float_as_uint(x - hf) >> 16);
}

// ---------------------------------------------------------------------------
// Tiled fp32 GEMM: C = A[M,1024] @ W[1024,1024] + bias.
// MODE 0: fp32 out [M,1024]  (final output projection)
// MODE 1: head-split bf16 hi/lo [B,H,S,64]   (Q, K)
// MODE 2: head-split TRANSPOSED bf16 hi/lo [B,H,64,S]  (V, for PV B-fragments)
// ---------------------------------------------------------------------------
template<int MODE>
__global__ __launch_bounds__(256)
void gemm_proj(const float* __restrict__ A, const float* __restrict__ W,
               const float* __restrict__ bias, float* __restrict__ Cf,
               u16* __restrict__ Chi, u16* __restrict__ Clo) {
  __shared__ float AsT[16][68];   // [k][row], +4 pad
  __shared__ float Bs[16][64];    // [k][col]
  const int tid = threadIdx.x;
  const int tx = tid & 15, ty = tid >> 4;
  const int row0 = blockIdx.x * 64;
  const int col0 = blockIdx.y * 64;
  float acc[4][4] = {};
  for (int k0 = 0; k0 < DMM; k0 += 16) {
    {
      const int r = tid >> 2;
      const int k4 = (tid & 3) << 2;
      float4 av = *(const float4*)(A + (size_t)(row0 + r) * DMM + k0 + k4);
      AsT[k4 + 0][r] = av.x; AsT[k4 + 1][r] = av.y;
      AsT[k4 + 2][r] = av.z; AsT[k4 + 3][r] = av.w;
    }
    {
      const int kr = tid >> 4;
      const int c4 = (tid & 15) << 2;
      *(float4*)&Bs[kr][c4] = *(const float4*)(W + (size_t)(k0 + kr) * DMM + col0 + c4);
    }
    __syncthreads();
#pragma unroll
    for (int k = 0; k < 16; ++k) {
      float4 a = *(const float4*)&AsT[k][ty << 2];
      float4 b = *(const float4*)&Bs[k][tx << 2];
      float av[4] = {a.x, a.y, a.z, a.w};
      float bv[4] = {b.x, b.y, b.z, b.w};
#pragma unroll
      for (int i = 0; i < 4; ++i)
#pragma unroll
        for (int j = 0; j < 4; ++j)
          acc[i][j] = fmaf(av[i], bv[j], acc[i][j]);
    }
    __syncthreads();
  }
  float4 bv4 = *(const float4*)(bias + col0 + (tx << 2));
  const float bb4[4] = {bv4.x, bv4.y, bv4.z, bv4.w};
  if (MODE == 0) {
#pragma unroll
    for (int i = 0; i < 4; ++i) {
      const int row = row0 + (ty << 2) + i;
      float4 o;
      o.x = acc[i][0] + bb4[0]; o.y = acc[i][1] + bb4[1];
      o.z = acc[i][2] + bb4[2]; o.w = acc[i][3] + bb4[3];
      *(float4*)(Cf + (size_t)row * DMM + col0 + (tx << 2)) = o;
    }
  } else if (MODE == 1) {
#pragma unroll
    for (int i = 0; i < 4; ++i) {
      const int row = row0 + (ty << 2) + i;
      const int b = row >> 11, s = row & (SS - 1);
      ushort4 h4, l4;
      bsplit(acc[i][0] + bb4[0], h4.x, l4.x);
      bsplit(acc[i][1] + bb4[1], h4.y, l4.y);
      bsplit(acc[i][2] + bb4[2], h4.z, l4.z);
      bsplit(acc[i][3] + bb4[3], h4.w, l4.w);
      const size_t base = (((size_t)(b * HH + blockIdx.y) * SS + s) << 6) + (tx << 2);
      *(ushort4*)(Chi + base) = h4;
      *(ushort4*)(Clo + base) = l4;
    }
  } else {  // MODE 2: vT[b][h][d][s]
    const int b = row0 >> 11;                      // 64-row block stays in one batch
    const int s0 = (row0 & (SS - 1)) + (ty << 2);
#pragma unroll
    for (int j = 0; j < 4; ++j) {
      const int d = (tx << 2) + j;
      ushort4 h4, l4;
      bsplit(acc[0][j] + bb4[j], h4.x, l4.x);
      bsplit(acc[1][j] + bb4[j], h4.y, l4.y);
      bsplit(acc[2][j] + bb4[j], h4.z, l4.z);
      bsplit(acc[3][j] + bb4[j], h4.w, l4.w);
      const size_t base = ((size_t)(b * HH + blockIdx.y) * DDEP + d) * SS + s0;
      *(ushort4*)(Chi + base) = h4;
      *(ushort4*)(Clo + base) = l4;
    }
  }
}

// ---------------------------------------------------------------------------
// Logits via bf16x3 MFMA: per (bh, 64-row block), loop 64-col K tiles.
// Writes raw logits; tracks online-softmax (m, l) per row.
// Fragment layout (16x16x32): A row=lane&15,k=(lane>>4)*8+i ; B col=lane&15,
// same k ; D col=lane&15,row=(lane>>4)*4+reg  [HW-verified m89/m91].
// LDS rows padded to 72 bf16 (144B = 9*16B): b128 reads aligned, <=2-way banks.
// ---------------------------------------------------------------------------
__global__ __launch_bounds__(256)
void attn_logits_mfma(const u16* __restrict__ qh_hi, const u16* __restrict__ qh_lo,
                      const u16* __restrict__ kh_hi, const u16* __restrict__ kh_lo,
                      const float* __restrict__ mask, float* __restrict__ attn,
                      float* __restrict__ mrow, float* __restrict__ lrow) {
  __shared__ u16 qs[2][64][72];   // [hi/lo][q-row][d]
  __shared__ u16 ks[2][64][72];   // [hi/lo][k-row][d]
  __shared__ float mkk[64];
  const int tid = threadIdx.x;
  const int lane = tid & 63, wid = tid >> 6;
  const int fr = lane & 15, kg = lane >> 4;
  const int rb = blockIdx.x, bh = blockIdx.y, b = bh >> 4;

  // stage Q block: 2 arrays x 64 rows x 8 chunks(16B) = 1024 chunks, 4/thread
  const size_t qbase = ((size_t)bh * SS + (size_t)rb * 64) << 6;
#pragma unroll
  for (int t = 0; t < 4; ++t) {
    const int idx = tid + t * 256;
    const int arr = idx >> 9, rem = idx & 511;
    const int r = rem >> 3, c8 = (rem & 7) << 3;
    const u16* src = (arr ? qh_lo : qh_hi) + qbase + (r << 6) + c8;
    *(u16x8*)&qs[arr][r][c8] = *(const u16x8*)src;
  }
  __syncthreads();
  // Q fragments are loop-invariant: hoist
  bf16x8 a_h[2], a_l[2];
#pragma unroll
  for (int ksi = 0; ksi < 2; ++ksi) {
    a_h[ksi] = *(const bf16x8*)&qs[0][wid * 16 + fr][ksi * 32 + kg * 8];
    a_l[ksi] = *(const bf16x8*)&qs[1][wid * 16 + fr][ksi * 32 + kg * 8];
  }
  float mt[4], lt[4];
#pragma unroll
  for (int j = 0; j < 4; ++j) { mt[j] = -1e30f; lt[j] = 0.f; }

  for (int cb = 0; cb < 32; ++cb) {
    const size_t kbase = ((size_t)bh * SS + (size_t)cb * 64) << 6;
#pragma unroll
    for (int t = 0; t < 4; ++t) {
      const int idx = tid + t * 256;
      const int arr = idx >> 9, rem = idx & 511;
      const int r = rem >> 3, c8 = (rem & 7) << 3;
      const u16* src = (arr ? kh_lo : kh_hi) + kbase + (r << 6) + c8;
      *(u16x8*)&ks[arr][r][c8] = *(const u16x8*)src;
    }
    if (tid < 64) mkk[tid] = mask[(size_t)b * SS + cb * 64 + tid] * -1e9f;
    __syncthreads();

    f32x4 acc[4];
#pragma unroll
    for (int ct = 0; ct < 4; ++ct) {
      bf16x8 b_h0 = *(const bf16x8*)&ks[0][ct * 16 + fr][kg * 8];
      bf16x8 b_h1 = *(const bf16x8*)&ks[0][ct * 16 + fr][32 + kg * 8];
      bf16x8 b_l0 = *(const bf16x8*)&ks[1][ct * 16 + fr][kg * 8];
      bf16x8 b_l1 = *(const bf16x8*)&ks[1][ct * 16 + fr][32 + kg * 8];
      f32x4 c = {0.f, 0.f, 0.f, 0.f};
      c = __builtin_amdgcn_mfma_f32_16x16x32_bf16(a_h[0], b_h0, c, 0, 0, 0);
      c = __builtin_amdgcn_mfma_f32_16x16x32_bf16(a_h[1], b_h1, c, 0, 0, 0);
      c = __builtin_amdgcn_mfma_f32_16x16x32_bf16(a_l[0], b_h0, c, 0, 0, 0);
      c = __builtin_amdgcn_mfma_f32_16x16x32_bf16(a_l[1], b_h1, c, 0, 0, 0);
      c = __builtin_amdgcn_mfma_f32_16x16x32_bf16(a_h[0], b_l0, c, 0, 0, 0);
      c = __builtin_amdgcn_mfma_f32_16x16x32_bf16(a_h[1], b_l1, c, 0, 0, 0);
      acc[ct] = c;
    }
    // epilogue: scale + mask, store raw logits, online (m,l)
    const int row_l = wid * 16 + kg * 4;
    float* abase = attn + ((size_t)bh * SS + rb * 64 + row_l) * SS + cb * 64 + fr;
    float mb[4];
#pragma unroll
    for (int ct = 0; ct < 4; ++ct) mb[ct] = mkk[ct * 16 + fr];
#pragma unroll
    for (int j = 0; j < 4; ++j) {
      float x0 = acc[0][j] * 0.125f + mb[0];
      float x1 = acc[1][j] * 0.125f + mb[1];
      float x2 = acc[2][j] * 0.125f + mb[2];
      float x3 = acc[3][j] * 0.125f + mb[3];
      abase[(size_t)j * SS + 0]  = x0;
      abase[(size_t)j * SS + 16] = x1;
      abase[(size_t)j * SS + 32] = x2;
      abase[(size_t)j * SS + 48] = x3;
      float mx = fmaxf(fmaxf(x0, x1), fmaxf(x2, x3));
      float mn = fmaxf(mt[j], mx);
      lt[j] = lt[j] * __expf(mt[j] - mn) +
              __expf(x0 - mn) + __expf(x1 - mn) + __expf(x2 - mn) + __expf(x3 - mn);
      mt[j] = mn;
    }
    __syncthreads();
  }
  // combine (m,l) across the 16 fr lanes holding each row
#pragma unroll
  for (int j = 0; j < 4; ++j) {
    float m = mt[j], l = lt[j];
#pragma unroll
    for (int off = 1; off < 16; off <<= 1) {
      float mo = __shfl_xor(m, off, 64);
      float lo = __shfl_xor(l, off, 64);
      float mn = fmaxf(m, mo);
      l = l * __expf(m - mn) + lo * __expf(mo - mn);
      m = mn;
    }
    if (fr == 0) {
      const int r = rb * 64 + wid * 16 + kg * 4 + j;
      mrow[(size_t)bh * SS + r] = m;
      lrow[(size_t)bh * SS + r] = l;
    }
  }
}

// ---------------------------------------------------------------------------
// PV via bf16x3 MFMA: re-read logits, finalize attn = exp(x-m)/l (write back),
// split p to bf16 hi/lo in LDS, ctx = attn @ vh using vT tiles.
// ---------------------------------------------------------------------------
__global__ __launch_bounds__(256)
void attn_pv_mfma(const u16* __restrict__ vt_hi, const u16* __restrict__ vt_lo,
                  const float* __restrict__ mrow, const float* __restrict__ lrow,
                  float* __restrict__ attn, float* __restrict__ ctx) {
  __shared__ u16 ps[2][64][72];   // [hi/lo][s-row][k]
  __shared__ u16 vs[2][64][72];   // [hi/lo][d][k]
  __shared__ float msm[64], rls[64];
  const int tid = threadIdx.x;
  const int lane = tid & 63, wid = tid >> 6;
  const int fr = lane & 15, kg = lane >> 4;
  const int rb = blockIdx.x, bh = blockIdx.y;
  const int b = bh >> 4, h = bh & 15;
  if (tid < 64) {
    const int r = rb * 64 + tid;
    msm[tid] = mrow[(size_t)bh * SS + r];
    rls[tid] = 1.f / lrow[(size_t)bh * SS + r];
  }
  __syncthreads();
  f32x4 acc[4];
#pragma unroll
  for (int ct = 0; ct < 4; ++ct) acc[ct] = (f32x4){0.f, 0.f, 0.f, 0.f};
  float* arow = attn + ((size_t)bh * SS + rb * 64) * SS;
  const size_t vbase = (size_t)bh * DDEP * SS;

  for (int cb = 0; cb < 32; ++cb) {
    // stage P: read logits, finalize, write back, split to LDS
#pragma unroll
    for (int t = 0; t < 4; ++t) {
      const int idx = tid + t * 256;
      const int r = idx >> 4, c4 = (idx & 15) << 2;
      float* ap = arow + (size_t)r * SS + cb * 64 + c4;
      float4 x = *(const float4*)ap;
      const float mm = msm[r], rl = rls[r];
      float4 p;
      p.x = __expf(x.x - mm) * rl;
      p.y = __expf(x.y - mm) * rl;
      p.z = __expf(x.z - mm) * rl;
      p.w = __expf(x.w - mm) * rl;
      *(float4*)ap = p;                 // final attn output
      ushort4 h4, l4;
      bsplit(p.x, h4.x, l4.x); bsplit(p.y, h4.y, l4.y);
      bsplit(p.z, h4.z, l4.z); bsplit(p.w, h4.w, l4.w);
      *(ushort4*)&ps[0][r][c4] = h4;
      *(ushort4*)&ps[1][r][c4] = l4;
    }
    // stage vT tile: [d][k] contiguous rows
#pragma unroll
    for (int t = 0; t < 4; ++t) {
      const int idx = tid + t * 256;
      const int arr = idx >> 9, rem = idx & 511;
      const int d = rem >> 3, c8 = (rem & 7) << 3;
      const u16* src = (arr ? vt_lo : vt_hi) + vbase + (size_t)d * SS + cb * 64 + c8;
      *(u16x8*)&vs[arr][d][c8] = *(const u16x8*)src;
    }
    __syncthreads();
    bf16x8 a_h[2], a_l[2];
#pragma unroll
    for (int ksi = 0; ksi < 2; ++ksi) {
      a_h[ksi] = *(const bf16x8*)&ps[0][wid * 16 + fr][ksi * 32 + kg * 8];
      a_l[ksi] = *(const bf16x8*)&ps[1][wid * 16 + fr][ksi * 32 + kg * 8];
    }
#pragma unroll
    for (int ct = 0; ct < 4; ++ct) {
      bf16x8 b_h0 = *(const bf16x8*)&vs[0][ct * 16 + fr][kg * 8];
      bf16x8 b_h1 = *(const bf16x8*)&vs[0][ct * 16 + fr][32 + kg * 8];
      bf16x8 b_l0 = *(const bf16x8*)&vs[1][ct * 16 + fr][kg * 8];
      bf16x8 b_l1 = *(const bf16x8*)&vs[1][ct * 16 + fr][32 + kg * 8];
      f32x4 c = acc[ct];
      c = __builtin_amdgcn_mfma_f32_16x16x32_bf16(a_h[0], b_h0, c, 0, 0, 0);
      c = __builtin_amdgcn_mfma_f32_16x16x32_bf16(a_h[1], b_h1, c, 0, 0, 0);
      c = __builtin_amdgcn_mfma_f32_16x16x32_bf16(a_l[0], b_h0, c, 0, 0, 0);
      c = __builtin_amdgcn_mfma_f32_16x16x32_bf16(a_l[1], b_h1, c, 0, 0, 0);
      c = __builtin_amdgcn_mfma_f32_16x16x32_bf16(a_h[0], b_l0, c, 0, 0, 0);
      c = __builtin_amdgcn_mfma_f32_16x16x32_bf16(a_h[1], b_l1, c, 0, 0, 0);
      acc[ct] = c;
    }
    __syncthreads();
  }
  // write ctx [B,S,DM] merged layout
  const int s_l = rb * 64 + wid * 16 + kg * 4;
#pragma unroll
  for (int ct = 0; ct < 4; ++ct)
#pragma unroll
    for (int j = 0; j < 4; ++j)
      ctx[((size_t)b * SS + s_l + j) * DMM + h * 64 + ct * 16 + fr] = acc[ct][j];
}

// ---------------------------------------------------------------------------
extern "C" void kernel_launch(void* const* d_in, const int* in_sizes, int n_in,
                              void* d_out, int out_size, void* d_ws, size_t ws_size,
                              hipStream_t stream) {
  const float* q    = (const float*)d_in[0];
  const float* k    = (const float*)d_in[1];
  const float* v    = (const float*)d_in[2];
  const float* mask = (const float*)d_in[3];
  const float* Wq   = (const float*)d_in[4];
  const float* bq   = (const float*)d_in[5];
  const float* Wk   = (const float*)d_in[6];
  const float* bk   = (const float*)d_in[7];
  const float* Wv   = (const float*)d_in[8];
  const float* bvp  = (const float*)d_in[9];
  const float* Wo   = (const float*)d_in[10];
  const float* bo   = (const float*)d_in[11];

  float* out  = (float*)d_out;                          // [B,S,DM]
  float* attn = out + (size_t)BB * SS * DMM;            // [B,H,S,S]

  const size_t PROJ = (size_t)BB * HH * SS * DDEP;      // 4,194,304
  const size_t BHS  = (size_t)BB * HH * SS;             // 65,536
  float* ws   = (float*)d_ws;
  float* ctx  = ws;                                     // PROJ fp32
  float* mrow = ctx + PROJ;
  float* lrow = mrow + BHS;
  u16*  qh_hi = (u16*)(lrow + BHS);                     // 6 x PROJ bf16
  u16*  qh_lo = qh_hi + PROJ;
  u16*  kh_hi = qh_lo + PROJ;
  u16*  kh_lo = kh_hi + PROJ;
  u16*  vt_hi = kh_lo + PROJ;
  u16*  vt_lo = vt_hi + PROJ;

  dim3 blk(256);
  dim3 g1(64, 16);   // 4096/64 row tiles x 1024/64 col tiles
  hipLaunchKernelGGL((gemm_proj<1>), g1, blk, 0, stream, q, Wq, bq, nullptr, qh_hi, qh_lo);
  hipLaunchKernelGGL((gemm_proj<1>), g1, blk, 0, stream, k, Wk, bk, nullptr, kh_hi, kh_lo);
  hipLaunchKernelGGL((gemm_proj<2>), g1, blk, 0, stream, v, Wv, bvp, nullptr, vt_hi, vt_lo);
  dim3 g2(32, 32);   // 32 q-row blocks x 32 (b,h)
  hipLaunchKernelGGL(attn_logits_mfma, g2, blk, 0, stream,
                     qh_hi, qh_lo, kh_hi, kh_lo, mask, attn, mrow, lrow);
  hipLaunchKernelGGL(attn_pv_mfma, g2, blk, 0, stream,
                     vt_hi, vt_lo, mrow, lrow, attn, ctx);
  hipLaunchKernelGGL((gemm_proj<0>), g1, blk, 0, stream, ctx, Wo, bo, out, nullptr, nullptr);
}

// Round 3
// 1121.526 us; speedup vs baseline: 1.4262x; 1.2840x over previous
//
#include <hip/hip_runtime.h>
#include <math.h>

#define BB 2
#define SS 2048
#define DMM 1024
#define HH 16
#define DDEP 64

typedef unsigned short u16;
typedef __attribute__((ext_vector_type(8))) short bf16x8;
typedef __attribute__((ext_vector_type(8))) unsigned short u16x8;
typedef __attribute__((ext_vector_type(4))) float f32x4;

// Split fp32 into truncated-bf16 hi + bf16(lo remainder). a ~= hi + lo with
// |a - hi - lo| <= 2^-16 |a|;  (ah+al)(bh+bl) ~= ah*bh + ah*bl + al*bh (drop lo*lo).
__device__ __forceinline__ void bsplit(float x, u16& h, u16& l) {
  unsigned u = __float_as_uint(x);
  h = (u16)(u >> 16);
  float hf = __uint_as_float(u & 0xFFFF0000u);
  l = (u16)(__float_as_uint(x - hf) >> 16);
}

// ---------------------------------------------------------------------------
// W [1024][1024] fp32 (k-major) -> WT_hi/WT_lo [n][k] bf16.  64x64 LDS tiles.
// ---------------------------------------------------------------------------
__global__ __launch_bounds__(256)
void split_wT(const float* __restrict__ W, u16* __restrict__ WTh,
              u16* __restrict__ WTl) {
  __shared__ float ts[64][65];
  const int tid = threadIdx.x;
  const int k0 = blockIdx.x * 64, n0 = blockIdx.y * 64;
#pragma unroll
  for (int t = 0; t < 4; ++t) {
    const int idx = tid + t * 256;
    const int kr = idx >> 4, n4 = (idx & 15) << 2;
    float4 v = *(const float4*)(W + (size_t)(k0 + kr) * DMM + n0 + n4);
    ts[kr][n4 + 0] = v.x; ts[kr][n4 + 1] = v.y;
    ts[kr][n4 + 2] = v.z; ts[kr][n4 + 3] = v.w;
  }
  __syncthreads();
#pragma unroll
  for (int t = 0; t < 4; ++t) {
    const int idx = tid + t * 256;
    const int n = idx >> 4, k4 = (idx & 15) << 2;
    ushort4 h4, l4;
    bsplit(ts[k4 + 0][n], h4.x, l4.x);
    bsplit(ts[k4 + 1][n], h4.y, l4.y);
    bsplit(ts[k4 + 2][n], h4.z, l4.z);
    bsplit(ts[k4 + 3][n], h4.w, l4.w);
    const size_t base = (size_t)(n0 + n) * DMM + k0 + k4;
    *(ushort4*)(WTh + base) = h4;
    *(ushort4*)(WTl + base) = l4;
  }
}

// ---------------------------------------------------------------------------
// bf16x3 MFMA GEMM: C = A[M,1024](fp32, split on the fly) @ W + bias,
// W given as pre-split/transposed WT hi/lo [n][k].
// 64x64 tile, 256 thr (4 waves), K-tile 64, 6 MFMAs per 16x16 sub-tile.
// MODE 0: fp32 out [M,1024]
// MODE 1: head-split bf16 hi/lo [B,H,S,64]   (Q, K)
// MODE 2: head-split TRANSPOSED bf16 hi/lo [B,H,64,S]  (V)
// ---------------------------------------------------------------------------
template<int MODE>
__global__ __launch_bounds__(256)
void gemm_mfma(const float* __restrict__ A, const u16* __restrict__ WTh,
               const u16* __restrict__ WTl, const float* __restrict__ bias,
               float* __restrict__ Cf, u16* __restrict__ Chi,
               u16* __restrict__ Clo) {
  __shared__ u16 as[2][64][72];   // [hi/lo][row][k]
  __shared__ u16 ws[2][64][72];   // [hi/lo][col][k]
  const int tid = threadIdx.x;
  const int lane = tid & 63, wid = tid >> 6;
  const int fr = lane & 15, kg = lane >> 4;
  const int row0 = blockIdx.x * 64;
  const int col0 = blockIdx.y * 64;
  f32x4 acc[4];
#pragma unroll
  for (int ct = 0; ct < 4; ++ct) acc[ct] = (f32x4){0.f, 0.f, 0.f, 0.f};

  for (int k0 = 0; k0 < DMM; k0 += 64) {
    // stage A tile: 64 rows x 64 k fp32, split to hi/lo
#pragma unroll
    for (int t = 0; t < 4; ++t) {
      const int idx = tid + t * 256;
      const int r = idx >> 4, c4 = (idx & 15) << 2;
      float4 v = *(const float4*)(A + (size_t)(row0 + r) * DMM + k0 + c4);
      ushort4 h4, l4;
      bsplit(v.x, h4.x, l4.x); bsplit(v.y, h4.y, l4.y);
      bsplit(v.z, h4.z, l4.z); bsplit(v.w, h4.w, l4.w);
      *(ushort4*)&as[0][r][c4] = h4;
      *(ushort4*)&as[1][r][c4] = l4;
    }
    // stage WT tile: 2 arrays x 64 cols x 64 k bf16
#pragma unroll
    for (int t = 0; t < 4; ++t) {
      const int idx = tid + t * 256;
      const int arr = idx >> 9, rem = idx & 511;
      const int c = rem >> 3, k8 = (rem & 7) << 3;
      const u16* src = (arr ? WTl : WTh) + (size_t)(col0 + c) * DMM + k0 + k8;
      *(u16x8*)&ws[arr][c][k8] = *(const u16x8*)src;
    }
    __syncthreads();
    bf16x8 a_h[2], a_l[2];
#pragma unroll
    for (int ksi = 0; ksi < 2; ++ksi) {
      a_h[ksi] = *(const bf16x8*)&as[0][wid * 16 + fr][ksi * 32 + kg * 8];
      a_l[ksi] = *(const bf16x8*)&as[1][wid * 16 + fr][ksi * 32 + kg * 8];
    }
#pragma unroll
    for (int ct = 0; ct < 4; ++ct) {
      bf16x8 b_h0 = *(const bf16x8*)&ws[0][ct * 16 + fr][kg * 8];
      bf16x8 b_h1 = *(const bf16x8*)&ws[0][ct * 16 + fr][32 + kg * 8];
      bf16x8 b_l0 = *(const bf16x8*)&ws[1][ct * 16 + fr][kg * 8];
      bf16x8 b_l1 = *(const bf16x8*)&ws[1][ct * 16 + fr][32 + kg * 8];
      f32x4 c = acc[ct];
      c = __builtin_amdgcn_mfma_f32_16x16x32_bf16(a_h[0], b_h0, c, 0, 0, 0);
      c = __builtin_amdgcn_mfma_f32_16x16x32_bf16(a_h[1], b_h1, c, 0, 0, 0);
      c = __builtin_amdgcn_mfma_f32_16x16x32_bf16(a_l[0], b_h0, c, 0, 0, 0);
      c = __builtin_amdgcn_mfma_f32_16x16x32_bf16(a_l[1], b_h1, c, 0, 0, 0);
      c = __builtin_amdgcn_mfma_f32_16x16x32_bf16(a_h[0], b_l0, c, 0, 0, 0);
      c = __builtin_amdgcn_mfma_f32_16x16x32_bf16(a_h[1], b_l1, c, 0, 0, 0);
      acc[ct] = c;
    }
    __syncthreads();
  }

  // epilogue: D col = ct*16+fr, row = wid*16 + kg*4 + j  [m89/m91 layout]
  const int row_l = wid * 16 + kg * 4;
  if (MODE == 0) {
#pragma unroll
    for (int ct = 0; ct < 4; ++ct) {
      const float bsv = bias[col0 + ct * 16 + fr];
#pragma unroll
      for (int j = 0; j < 4; ++j)
        Cf[(size_t)(row0 + row_l + j) * DMM + col0 + ct * 16 + fr] =
            acc[ct][j] + bsv;
    }
  } else if (MODE == 1) {
#pragma unroll
    for (int ct = 0; ct < 4; ++ct) {
      const float bsv = bias[col0 + ct * 16 + fr];
#pragma unroll
      for (int j = 0; j < 4; ++j) {
        const int row = row0 + row_l + j;
        const int b = row >> 11, s = row & (SS - 1);
        u16 h, l;
        bsplit(acc[ct][j] + bsv, h, l);
        const size_t base =
            (((size_t)(b * HH + blockIdx.y) * SS + s) << 6) + ct * 16 + fr;
        Chi[base] = h;
        Clo[base] = l;
      }
    }
  } else {  // MODE 2: vT[b][h][d][s], 64-row block stays in one batch
    const int b = row0 >> 11;
    const int s0 = (row0 & (SS - 1)) + row_l;
#pragma unroll
    for (int ct = 0; ct < 4; ++ct) {
      const int d = ct * 16 + fr;
      const float bsv = bias[col0 + d];
      ushort4 h4, l4;
      bsplit(acc[ct][0] + bsv, h4.x, l4.x);
      bsplit(acc[ct][1] + bsv, h4.y, l4.y);
      bsplit(acc[ct][2] + bsv, h4.z, l4.z);
      bsplit(acc[ct][3] + bsv, h4.w, l4.w);
      const size_t base =
          (((size_t)(b * HH + blockIdx.y) * DDEP + d) << 11) + s0;
      *(ushort4*)(Chi + base) = h4;
      *(ushort4*)(Clo + base) = l4;
    }
  }
}

// ---------------------------------------------------------------------------
// Logits via bf16x3 MFMA (unchanged from passing round-2 version).
// ---------------------------------------------------------------------------
__global__ __launch_bounds__(256)
void attn_logits_mfma(const u16* __restrict__ qh_hi, const u16* __restrict__ qh_lo,
                      const u16* __restrict__ kh_hi, const u16* __restrict__ kh_lo,
                      const float* __restrict__ mask, float* __restrict__ attn,
                      float* __restrict__ mrow, float* __restrict__ lrow) {
  __shared__ u16 qs[2][64][72];   // [hi/lo][q-row][d]
  __shared__ u16 ks[2][64][72];   // [hi/lo][k-row][d]
  __shared__ float mkk[64];
  const int tid = threadIdx.x;
  const int lane = tid & 63, wid = tid >> 6;
  const int fr = lane & 15, kg = lane >> 4;
  const int rb = blockIdx.x, bh = blockIdx.y, b = bh >> 4;

  const size_t qbase = ((size_t)bh * SS + (size_t)rb * 64) << 6;
#pragma unroll
  for (int t = 0; t < 4; ++t) {
    const int idx = tid + t * 256;
    const int arr = idx >> 9, rem = idx & 511;
    const int r = rem >> 3, c8 = (rem & 7) << 3;
    const u16* src = (arr ? qh_lo : qh_hi) + qbase + (r << 6) + c8;
    *(u16x8*)&qs[arr][r][c8] = *(const u16x8*)src;
  }
  __syncthreads();
  bf16x8 a_h[2], a_l[2];
#pragma unroll
  for (int ksi = 0; ksi < 2; ++ksi) {
    a_h[ksi] = *(const bf16x8*)&qs[0][wid * 16 + fr][ksi * 32 + kg * 8];
    a_l[ksi] = *(const bf16x8*)&qs[1][wid * 16 + fr][ksi * 32 + kg * 8];
  }
  float mt[4], lt[4];
#pragma unroll
  for (int j = 0; j < 4; ++j) { mt[j] = -1e30f; lt[j] = 0.f; }

  for (int cb = 0; cb < 32; ++cb) {
    const size_t kbase = ((size_t)bh * SS + (size_t)cb * 64) << 6;
#pragma unroll
    for (int t = 0; t < 4; ++t) {
      const int idx = tid + t * 256;
      const int arr = idx >> 9, rem = idx & 511;
      const int r = rem >> 3, c8 = (rem & 7) << 3;
      const u16* src = (arr ? kh_lo : kh_hi) + kbase + (r << 6) + c8;
      *(u16x8*)&ks[arr][r][c8] = *(const u16x8*)src;
    }
    if (tid < 64) mkk[tid] = mask[(size_t)b * SS + cb * 64 + tid] * -1e9f;
    __syncthreads();

    f32x4 acc[4];
#pragma unroll
    for (int ct = 0; ct < 4; ++ct) {
      bf16x8 b_h0 = *(const bf16x8*)&ks[0][ct * 16 + fr][kg * 8];
      bf16x8 b_h1 = *(const bf16x8*)&ks[0][ct * 16 + fr][32 + kg * 8];
      bf16x8 b_l0 = *(const bf16x8*)&ks[1][ct * 16 + fr][kg * 8];
      bf16x8 b_l1 = *(const bf16x8*)&ks[1][ct * 16 + fr][32 + kg * 8];
      f32x4 c = {0.f, 0.f, 0.f, 0.f};
      c = __builtin_amdgcn_mfma_f32_16x16x32_bf16(a_h[0], b_h0, c, 0, 0, 0);
      c = __builtin_amdgcn_mfma_f32_16x16x32_bf16(a_h[1], b_h1, c, 0, 0, 0);
      c = __builtin_amdgcn_mfma_f32_16x16x32_bf16(a_l[0], b_h0, c, 0, 0, 0);
      c = __builtin_amdgcn_mfma_f32_16x16x32_bf16(a_l[1], b_h1, c, 0, 0, 0);
      c = __builtin_amdgcn_mfma_f32_16x16x32_bf16(a_h[0], b_l0, c, 0, 0, 0);
      c = __builtin_amdgcn_mfma_f32_16x16x32_bf16(a_h[1], b_l1, c, 0, 0, 0);
      acc[ct] = c;
    }
    const int row_l = wid * 16 + kg * 4;
    float* abase = attn + ((size_t)bh * SS + rb * 64 + row_l) * SS + cb * 64 + fr;
    float mb[4];
#pragma unroll
    for (int ct = 0; ct < 4; ++ct) mb[ct] = mkk[ct * 16 + fr];
#pragma unroll
    for (int j = 0; j < 4; ++j) {
      float x0 = acc[0][j] * 0.125f + mb[0];
      float x1 = acc[1][j] * 0.125f + mb[1];
      float x2 = acc[2][j] * 0.125f + mb[2];
      float x3 = acc[3][j] * 0.125f + mb[3];
      abase[(size_t)j * SS + 0]  = x0;
      abase[(size_t)j * SS + 16] = x1;
      abase[(size_t)j * SS + 32] = x2;
      abase[(size_t)j * SS + 48] = x3;
      float mx = fmaxf(fmaxf(x0, x1), fmaxf(x2, x3));
      float mn = fmaxf(mt[j], mx);
      lt[j] = lt[j] * __expf(mt[j] - mn) +
              __expf(x0 - mn) + __expf(x1 - mn) + __expf(x2 - mn) + __expf(x3 - mn);
      mt[j] = mn;
    }
    __syncthreads();
  }
#pragma unroll
  for (int j = 0; j < 4; ++j) {
    float m = mt[j], l = lt[j];
#pragma unroll
    for (int off = 1; off < 16; off <<= 1) {
      float mo = __shfl_xor(m, off, 64);
      float lo = __shfl_xor(l, off, 64);
      float mn = fmaxf(m, mo);
      l = l * __expf(m - mn) + lo * __expf(mo - mn);
      m = mn;
    }
    if (fr == 0) {
      const int r = rb * 64 + wid * 16 + kg * 4 + j;
      mrow[(size_t)bh * SS + r] = m;
      lrow[(size_t)bh * SS + r] = l;
    }
  }
}

// ---------------------------------------------------------------------------
// PV via bf16x3 MFMA (unchanged from passing round-2 version).
// ---------------------------------------------------------------------------
__global__ __launch_bounds__(256)
void attn_pv_mfma(const u16* __restrict__ vt_hi, const u16* __restrict__ vt_lo,
                  const float* __restrict__ mrow, const float* __restrict__ lrow,
                  float* __restrict__ attn, float* __restrict__ ctx) {
  __shared__ u16 ps[2][64][72];   // [hi/lo][s-row][k]
  __shared__ u16 vs[2][64][72];   // [hi/lo][d][k]
  __shared__ float msm[64], rls[64];
  const int tid = threadIdx.x;
  const int lane = tid & 63, wid = tid >> 6;
  const int fr = lane & 15, kg = lane >> 4;
  const int rb = blockIdx.x, bh = blockIdx.y;
  const int b = bh >> 4, h = bh & 15;
  if (tid < 64) {
    const int r = rb * 64 + tid;
    msm[tid] = mrow[(size_t)bh * SS + r];
    rls[tid] = 1.f / lrow[(size_t)bh * SS + r];
  }
  __syncthreads();
  f32x4 acc[4];
#pragma unroll
  for (int ct = 0; ct < 4; ++ct) acc[ct] = (f32x4){0.f, 0.f, 0.f, 0.f};
  float* arow = attn + ((size_t)bh * SS + rb * 64) * SS;
  const size_t vbase = (size_t)bh * DDEP * SS;

  for (int cb = 0; cb < 32; ++cb) {
#pragma unroll
    for (int t = 0; t < 4; ++t) {
      const int idx = tid + t * 256;
      const int r = idx >> 4, c4 = (idx & 15) << 2;
      float* ap = arow + (size_t)r * SS + cb * 64 + c4;
      float4 x = *(const float4*)ap;
      const float mm = msm[r], rl = rls[r];
      float4 p;
      p.x = __expf(x.x - mm) * rl;
      p.y = __expf(x.y - mm) * rl;
      p.z = __expf(x.z - mm) * rl;
      p.w = __expf(x.w - mm) * rl;
      *(float4*)ap = p;                 // final attn output
      ushort4 h4, l4;
      bsplit(p.x, h4.x, l4.x); bsplit(p.y, h4.y, l4.y);
      bsplit(p.z, h4.z, l4.z); bsplit(p.w, h4.w, l4.w);
      *(ushort4*)&ps[0][r][c4] = h4;
      *(ushort4*)&ps[1][r][c4] = l4;
    }
#pragma unroll
    for (int t = 0; t < 4; ++t) {
      const int idx = tid + t * 256;
      const int arr = idx >> 9, rem = idx & 511;
      const int d = rem >> 3, c8 = (rem & 7) << 3;
      const u16* src = (arr ? vt_lo : vt_hi) + vbase + (size_t)d * SS + cb * 64 + c8;
      *(u16x8*)&vs[arr][d][c8] = *(const u16x8*)src;
    }
    __syncthreads();
    bf16x8 a_h[2], a_l[2];
#pragma unroll
    for (int ksi = 0; ksi < 2; ++ksi) {
      a_h[ksi] = *(const bf16x8*)&ps[0][wid * 16 + fr][ksi * 32 + kg * 8];
      a_l[ksi] = *(const bf16x8*)&ps[1][wid * 16 + fr][ksi * 32 + kg * 8];
    }
#pragma unroll
    for (int ct = 0; ct < 4; ++ct) {
      bf16x8 b_h0 = *(const bf16x8*)&vs[0][ct * 16 + fr][kg * 8];
      bf16x8 b_h1 = *(const bf16x8*)&vs[0][ct * 16 + fr][32 + kg * 8];
      bf16x8 b_l0 = *(const bf16x8*)&vs[1][ct * 16 + fr][kg * 8];
      bf16x8 b_l1 = *(const bf16x8*)&vs[1][ct * 16 + fr][32 + kg * 8];
      f32x4 c = acc[ct];
      c = __builtin_amdgcn_mfma_f32_16x16x32_bf16(a_h[0], b_h0, c, 0, 0, 0);
      c = __builtin_amdgcn_mfma_f32_16x16x32_bf16(a_h[1], b_h1, c, 0, 0, 0);
      c = __builtin_amdgcn_mfma_f32_16x16x32_bf16(a_l[0], b_h0, c, 0, 0, 0);
      c = __builtin_amdgcn_mfma_f32_16x16x32_bf16(a_l[1], b_h1, c, 0, 0, 0);
      c = __builtin_amdgcn_mfma_f32_16x16x32_bf16(a_h[0], b_l0, c, 0, 0, 0);
      c = __builtin_amdgcn_mfma_f32_16x16x32_bf16(a_h[1], b_l1, c, 0, 0, 0);
      acc[ct] = c;
    }
    __syncthreads();
  }
  const int s_l = rb * 64 + wid * 16 + kg * 4;
#pragma unroll
  for (int ct = 0; ct < 4; ++ct)
#pragma unroll
    for (int j = 0; j < 4; ++j)
      ctx[((size_t)b * SS + s_l + j) * DMM + h * 64 + ct * 16 + fr] = acc[ct][j];
}

// ---------------------------------------------------------------------------
extern "C" void kernel_launch(void* const* d_in, const int* in_sizes, int n_in,
                              void* d_out, int out_size, void* d_ws, size_t ws_size,
                              hipStream_t stream) {
  const float* q    = (const float*)d_in[0];
  const float* k    = (const float*)d_in[1];
  const float* v    = (const float*)d_in[2];
  const float* mask = (const float*)d_in[3];
  const float* Wq   = (const float*)d_in[4];
  const float* bq   = (const float*)d_in[5];
  const float* Wk   = (const float*)d_in[6];
  const float* bk   = (const float*)d_in[7];
  const float* Wv   = (const float*)d_in[8];
  const float* bvp  = (const float*)d_in[9];
  const float* Wo   = (const float*)d_in[10];
  const float* bo   = (const float*)d_in[11];

  float* out  = (float*)d_out;                          // [B,S,DM]
  float* attn = out + (size_t)BB * SS * DMM;            // [B,H,S,S]

  const size_t PROJ  = (size_t)BB * HH * SS * DDEP;     // 4,194,304
  const size_t PROJW = (size_t)DMM * DMM;               // 1,048,576
  const size_t BHS   = (size_t)BB * HH * SS;            // 65,536

  u16* wt_hi = (u16*)d_ws;                              // reused for all 4 Ws
  u16* wt_lo = wt_hi + PROJW;
  u16* qh_hi = wt_lo + PROJW;
  u16* qh_lo = qh_hi + PROJ;
  u16* kh_hi = qh_lo + PROJ;
  u16* kh_lo = kh_hi + PROJ;
  u16* vt_hi = kh_lo + PROJ;
  u16* vt_lo = vt_hi + PROJ;
  float* mrow = (float*)(vt_lo + PROJ);
  float* lrow = mrow + BHS;
  float* ctx  = (float*)kh_hi;   // aliases kh hi+lo (16 MB); kh dead after logits

  dim3 blk(256);
  dim3 gw(16, 16);   // 1024/64 x 1024/64 for split_wT
  dim3 g1(64, 16);   // 4096/64 row tiles x 1024/64 col tiles
  dim3 g2(32, 32);   // 32 q-row blocks x 32 (b,h)

  hipLaunchKernelGGL(split_wT, gw, blk, 0, stream, Wq, wt_hi, wt_lo);
  hipLaunchKernelGGL((gemm_mfma<1>), g1, blk, 0, stream,
                     q, wt_hi, wt_lo, bq, nullptr, qh_hi, qh_lo);
  hipLaunchKernelGGL(split_wT, gw, blk, 0, stream, Wk, wt_hi, wt_lo);
  hipLaunchKernelGGL((gemm_mfma<1>), g1, blk, 0, stream,
                     k, wt_hi, wt_lo, bk, nullptr, kh_hi, kh_lo);
  hipLaunchKernelGGL(split_wT, gw, blk, 0, stream, Wv, wt_hi, wt_lo);
  hipLaunchKernelGGL((gemm_mfma<2>), g1, blk, 0, stream,
                     v, wt_hi, wt_lo, bvp, nullptr, vt_hi, vt_lo);
  hipLaunchKernelGGL(attn_logits_mfma, g2, blk, 0, stream,
                     qh_hi, qh_lo, kh_hi, kh_lo, mask, attn, mrow, lrow);
  hipLaunchKernelGGL(attn_pv_mfma, g2, blk, 0, stream,
                     vt_hi, vt_lo, mrow, lrow, attn, ctx);
  hipLaunchKernelGGL(split_wT, gw, blk, 0, stream, Wo, wt_hi, wt_lo);
  hipLaunchKernelGGL((gemm_mfma<0>), g1, blk, 0, stream,
                     ctx, wt_hi, wt_lo, bo, out, nullptr, nullptr);
}